// Round 1
// baseline (248.630 us; speedup 1.0000x reference)
//
#include <hip/hip_runtime.h>
#include <hip/hip_bf16.h>

// B=4, S=2048, D=1024. x:[4,2048,1024] f32; wq/wk/wv:[1024,1024] f32.
// out:[4,2048,1024] f32.
//
// Pipeline (all bf16 MFMA with fp32 accumulation):
//   1. convx:  x f32 -> xb bf16                    [8192,1024]
//   2. wtrans: wq/wk/wv f32 -> wt bf16 TRANSPOSED  [3][1024(n)][1024(k)]
//   3. gemm<0>: qb/kb/vb = xb @ wt^T (NT)          bf16 out
//   4. vtrans: vb -> vt bf16 transposed            [4][1024(d)][2048(s)]
//   5. gemm<1>: scores = (qb @ kb^T)/32, causal block-skip, f32 out
//   6. softmax: per-row causal softmax, writes bf16 attn in-place over scores
//   7. gemm<2>: out = attn @ vt^T (NT, K truncated at diagonal), f32 out

typedef __attribute__((ext_vector_type(8))) short bf16x8;
typedef __attribute__((ext_vector_type(4))) float f32x4;

__device__ __forceinline__ short f2bf(float f) {
    union { float f; unsigned u; } v; v.f = f;
    unsigned r = v.u + 0x7FFFu + ((v.u >> 16) & 1u);
    return (short)(r >> 16);
}

// ---------------- convert x to bf16 ----------------
__global__ __launch_bounds__(256) void convx(const float* __restrict__ x,
                                             short* __restrict__ xb, int n4) {
    int i = blockIdx.x * 256 + threadIdx.x;
    if (i < n4) {
        float4 v = ((const float4*)x)[i];
        short4 o;
        o.x = f2bf(v.x); o.y = f2bf(v.y); o.z = f2bf(v.z); o.w = f2bf(v.w);
        ((short4*)xb)[i] = o;
    }
}

// ---------------- weights: f32 [k][n] -> bf16 [n][k] ----------------
__global__ __launch_bounds__(256) void wtrans(const float* __restrict__ wq,
                                              const float* __restrict__ wk,
                                              const float* __restrict__ wv,
                                              short* __restrict__ wt) {
    int w = blockIdx.z;
    const float* W = (w == 0) ? wq : (w == 1) ? wk : wv;
    short* O = wt + (size_t)w * 1048576;
    int n0 = blockIdx.x * 64, k0 = blockIdx.y * 64;
    __shared__ float tile[64][65];
    int t = threadIdx.x;
#pragma unroll
    for (int i = 0; i < 16; ++i) {
        int idx = t + i * 256;
        int r = idx >> 6, c = idx & 63;
        tile[r][c] = W[(size_t)(k0 + r) * 1024 + n0 + c];
    }
    __syncthreads();
#pragma unroll
    for (int i = 0; i < 16; ++i) {
        int idx = t + i * 256;
        int r = idx >> 6, c = idx & 63;
        O[(size_t)(n0 + r) * 1024 + k0 + c] = f2bf(tile[c][r]);
    }
}

// ---------------- V: bf16 [b][s][d] -> bf16 [b][d][s] ----------------
__global__ __launch_bounds__(256) void vtrans(const short* __restrict__ vb,
                                              short* __restrict__ vt) {
    int b = blockIdx.z;
    int s0 = blockIdx.x * 64, d0 = blockIdx.y * 64;
    const short* V = vb + (size_t)b * 2048 * 1024;
    short* O = vt + (size_t)b * 1024 * 2048;
    __shared__ short tile[64][65];
    int t = threadIdx.x;
#pragma unroll
    for (int i = 0; i < 16; ++i) {
        int idx = t + i * 256;
        int r = idx >> 6, c = idx & 63;
        tile[r][c] = V[(size_t)(s0 + r) * 1024 + d0 + c];
    }
    __syncthreads();
#pragma unroll
    for (int i = 0; i < 16; ++i) {
        int idx = t + i * 256;
        int r = idx >> 6, c = idx & 63;
        O[(size_t)(d0 + r) * 2048 + s0 + c] = tile[c][r];
    }
}

// ---------------- NT GEMM: C[m][n] = sum_k A[m][k]*B[n][k] ----------------
// MODE 0: bf16 out (QKV).  MODE 1: f32 out, *scale, causal (skip col>row and
// skip blocks fully above diagonal).  MODE 2: f32 out, K truncated at m0+128.
template <int MODE>
__global__ __launch_bounds__(256) void gemm_nt(
    const short* __restrict__ A0, int lda, size_t sAz,
    const short* __restrict__ B0, int ldb, size_t sBz,
    void* __restrict__ C0, int ldc, size_t sCzBytes,
    int Ktotal, float scale) {

    const int m0 = blockIdx.y * 128;
    const int n0 = blockIdx.x * 128;
    if (MODE == 1 && n0 > m0 + 127) return;  // fully above diagonal

    const short* Ab = A0 + (size_t)blockIdx.z * sAz;
    const short* Bb = B0 + (size_t)blockIdx.z * sBz;
    char* Cb = (char*)C0 + (size_t)blockIdx.z * sCzBytes;

    const int tid = threadIdx.x;
    const int lane = tid & 63;
    const int wid = tid >> 6;
    const int wm = wid >> 1, wn = wid & 1;  // 2x2 waves, each 64x64

    __shared__ __align__(16) short As[128 * 40];  // +8 pad breaks bank conflicts
    __shared__ __align__(16) short Bs[128 * 40];

    f32x4 acc[4][4] = {};

    const int Kend = (MODE == 2) ? (m0 + 128 < Ktotal ? m0 + 128 : Ktotal) : Ktotal;
    const int r = lane & 15;
    const int kk = (lane >> 4) * 8;

    for (int k0 = 0; k0 < Kend; k0 += 32) {
        __syncthreads();
#pragma unroll
        for (int i = 0; i < 2; ++i) {
            int idx = tid + i * 256;
            int row = idx >> 2;
            int kc = (idx & 3) * 8;
            *(int4*)&As[row * 40 + kc] =
                *(const int4*)&Ab[(size_t)(m0 + row) * lda + k0 + kc];
            *(int4*)&Bs[row * 40 + kc] =
                *(const int4*)&Bb[(size_t)(n0 + row) * ldb + k0 + kc];
        }
        __syncthreads();

        bf16x8 a[4], b[4];
#pragma unroll
        for (int mi = 0; mi < 4; ++mi)
            a[mi] = *(bf16x8*)&As[(wm * 64 + mi * 16 + r) * 40 + kk];
#pragma unroll
        for (int ni = 0; ni < 4; ++ni)
            b[ni] = *(bf16x8*)&Bs[(wn * 64 + ni * 16 + r) * 40 + kk];
#pragma unroll
        for (int mi = 0; mi < 4; ++mi)
#pragma unroll
            for (int ni = 0; ni < 4; ++ni)
                acc[mi][ni] = __builtin_amdgcn_mfma_f32_16x16x32_bf16(
                    a[mi], b[ni], acc[mi][ni], 0, 0, 0);
    }

    // epilogue: C/D layout col=lane&15, row=(lane>>4)*4+reg
    const int r4 = (lane >> 4) * 4;
    const int c = lane & 15;
#pragma unroll
    for (int mi = 0; mi < 4; ++mi) {
#pragma unroll
        for (int ni = 0; ni < 4; ++ni) {
            int col = n0 + wn * 64 + ni * 16 + c;
#pragma unroll
            for (int i = 0; i < 4; ++i) {
                int rr = m0 + wm * 64 + mi * 16 + r4 + i;
                float v = acc[mi][ni][i];
                if (MODE == 0) {
                    ((short*)Cb)[(size_t)rr * ldc + col] = f2bf(v);
                } else if (MODE == 1) {
                    if (col <= rr)
                        ((float*)Cb)[(size_t)rr * ldc + col] = v * scale;
                } else {
                    ((float*)Cb)[(size_t)rr * ldc + col] = v;
                }
            }
        }
    }
}

// ---------------- causal row softmax, f32 scores -> bf16 attn in-place ------
__global__ __launch_bounds__(256) void softmax_causal(float* __restrict__ scores) {
    int row = blockIdx.x;            // 0..8191
    int b = row >> 11, i = row & 2047;
    float* srow = scores + ((size_t)b * 2048 + i) * 2048;
    short* arow = (short*)srow;      // bf16 written over the same row
    __shared__ float sv[2048];
    __shared__ float red[8];
    int t = threadIdx.x;
    int L = i + 1;

    float mx = -1e30f;
    for (int j = t; j < L; j += 256) {
        float v = srow[j];
        sv[j] = v;
        mx = fmaxf(mx, v);
    }
#pragma unroll
    for (int o = 32; o > 0; o >>= 1) mx = fmaxf(mx, __shfl_down(mx, o));
    if ((t & 63) == 0) red[t >> 6] = mx;
    __syncthreads();
    mx = fmaxf(fmaxf(red[0], red[1]), fmaxf(red[2], red[3]));

    float sum = 0.f;
    for (int j = t; j < L; j += 256) {
        float e = __expf(sv[j] - mx);
        sv[j] = e;
        sum += e;
    }
#pragma unroll
    for (int o = 32; o > 0; o >>= 1) sum += __shfl_down(sum, o);
    if ((t & 63) == 0) red[4 + (t >> 6)] = sum;
    __syncthreads();
    sum = red[4] + red[5] + red[6] + red[7];
    float rinv = 1.0f / sum;

    int Lpad = (i | 127) + 1;  // zero-fill up to the 128-block edge for PV
    for (int j = t; j < Lpad; j += 256) {
        float p = (j < L) ? sv[j] * rinv : 0.0f;
        arow[j] = f2bf(p);
    }
}

extern "C" void kernel_launch(void* const* d_in, const int* in_sizes, int n_in,
                              void* d_out, int out_size, void* d_ws, size_t ws_size,
                              hipStream_t stream) {
    const float* x  = (const float*)d_in[0];
    const float* wq = (const float*)d_in[1];
    const float* wk = (const float*)d_in[2];
    const float* wv = (const float*)d_in[3];
    float* out = (float*)d_out;

    // workspace layout (shorts)
    short* ws16 = (short*)d_ws;
    short* xb = ws16;                    //  8,388,608 shorts (16.78 MB)
    short* wt = xb + 8388608;            //  3,145,728
    short* qb = wt + 3145728;            //  8,388,608
    short* kb = qb + 8388608;            //  8,388,608
    short* vb = kb + 8388608;            //  8,388,608
    float* scores = (float*)(vb + 8388608);  // 4*2048*2048 f32 (67.1 MB)
    short* vt = xb;                      // reuse xb after QKV GEMM

    convx<<<8192, 256, 0, stream>>>(x, xb, 2097152);
    wtrans<<<dim3(16, 16, 3), 256, 0, stream>>>(wq, wk, wv, wt);
    // QKV: [8192,1024] = xb @ wt^T ; z selects weight & output
    gemm_nt<0><<<dim3(8, 64, 3), 256, 0, stream>>>(
        xb, 1024, (size_t)0,
        wt, 1024, (size_t)1048576,
        qb, 1024, (size_t)16777216,
        1024, 1.0f);
    vtrans<<<dim3(32, 16, 4), 256, 0, stream>>>(vb, vt);
    // scores = (q @ k^T) / 32, causal
    gemm_nt<1><<<dim3(16, 16, 4), 256, 0, stream>>>(
        qb, 1024, (size_t)2097152,
        kb, 1024, (size_t)2097152,
        scores, 2048, (size_t)16777216,
        1024, 0.03125f);
    softmax_causal<<<8192, 256, 0, stream>>>(scores);
    // out = attn @ vt^T, K truncated at diagonal; attn lda=4096 (in-place rows)
    gemm_nt<2><<<dim3(8, 16, 4), 256, 0, stream>>>(
        (const short*)scores, 4096, (size_t)8388608,
        vt, 2048, (size_t)2097152,
        out, 1024, (size_t)8388608,
        2048, 1.0f);
}

// Round 2
// 233.724 us; speedup vs baseline: 1.0638x; 1.0638x over previous
//
#include <hip/hip_runtime.h>
#include <hip/hip_bf16.h>

// B=4, S=2048, D=1024. x:[4,2048,1024] f32; wq/wk/wv:[1024,1024] f32.
// out:[4,2048,1024] f32.
//
// Pipeline (all bf16 MFMA with fp32 accumulation):
//   1. convx:  x f32 -> xb bf16                    [8192,1024]
//   2. wtrans: wq/wk/wv f32 -> wt bf16 TRANSPOSED  [3][1024(n)][1024(k)]
//   3. gemm<0>: qb/kb/vb = xb @ wt^T (NT)          bf16 out
//   4. vtrans: vb -> vt bf16 transposed            [4][1024(d)][2048(s)]
//   5. gemm<1>: scores = (qb @ kb^T)/32, causal block-skip, f32 out
//   6. softmax: per-row causal softmax, writes bf16 attn in-place over scores
//   7. gemm<2>: out = attn @ vt^T (NT, K truncated at diagonal), f32 out
//
// R2 change: gemm_nt staging now uses __builtin_amdgcn_global_load_lds
// width=16 (m97 structure: linear LDS [128][32], no pad — DMA requires
// wave-uniform base + lane*16 contiguous dest). Ladder-predicted ~874 TF
// class vs previous ~330-570 TF register-staged structure.

typedef __attribute__((ext_vector_type(8))) short bf16x8;
typedef __attribute__((ext_vector_type(4))) float f32x4;

#define GLOAD_LDS16(g, l)                                                     \
    __builtin_amdgcn_global_load_lds(                                         \
        (const __attribute__((address_space(1))) void*)(g),                   \
        (__attribute__((address_space(3))) void*)(l), 16, 0, 0)

__device__ __forceinline__ short f2bf(float f) {
    union { float f; unsigned u; } v; v.f = f;
    unsigned r = v.u + 0x7FFFu + ((v.u >> 16) & 1u);
    return (short)(r >> 16);
}

// ---------------- convert x to bf16 ----------------
__global__ __launch_bounds__(256) void convx(const float* __restrict__ x,
                                             short* __restrict__ xb, int n4) {
    int i = blockIdx.x * 256 + threadIdx.x;
    if (i < n4) {
        float4 v = ((const float4*)x)[i];
        short4 o;
        o.x = f2bf(v.x); o.y = f2bf(v.y); o.z = f2bf(v.z); o.w = f2bf(v.w);
        ((short4*)xb)[i] = o;
    }
}

// ---------------- weights: f32 [k][n] -> bf16 [n][k] ----------------
__global__ __launch_bounds__(256) void wtrans(const float* __restrict__ wq,
                                              const float* __restrict__ wk,
                                              const float* __restrict__ wv,
                                              short* __restrict__ wt) {
    int w = blockIdx.z;
    const float* W = (w == 0) ? wq : (w == 1) ? wk : wv;
    short* O = wt + (size_t)w * 1048576;
    int n0 = blockIdx.x * 64, k0 = blockIdx.y * 64;
    __shared__ float tile[64][65];
    int t = threadIdx.x;
#pragma unroll
    for (int i = 0; i < 16; ++i) {
        int idx = t + i * 256;
        int r = idx >> 6, c = idx & 63;
        tile[r][c] = W[(size_t)(k0 + r) * 1024 + n0 + c];
    }
    __syncthreads();
#pragma unroll
    for (int i = 0; i < 16; ++i) {
        int idx = t + i * 256;
        int r = idx >> 6, c = idx & 63;
        O[(size_t)(n0 + r) * 1024 + k0 + c] = f2bf(tile[c][r]);
    }
}

// ---------------- V: bf16 [b][s][d] -> bf16 [b][d][s] ----------------
__global__ __launch_bounds__(256) void vtrans(const short* __restrict__ vb,
                                              short* __restrict__ vt) {
    int b = blockIdx.z;
    int s0 = blockIdx.x * 64, d0 = blockIdx.y * 64;
    const short* V = vb + (size_t)b * 2048 * 1024;
    short* O = vt + (size_t)b * 1024 * 2048;
    __shared__ short tile[64][65];
    int t = threadIdx.x;
#pragma unroll
    for (int i = 0; i < 16; ++i) {
        int idx = t + i * 256;
        int r = idx >> 6, c = idx & 63;
        tile[r][c] = V[(size_t)(s0 + r) * 1024 + d0 + c];
    }
    __syncthreads();
#pragma unroll
    for (int i = 0; i < 16; ++i) {
        int idx = t + i * 256;
        int r = idx >> 6, c = idx & 63;
        O[(size_t)(d0 + r) * 2048 + s0 + c] = tile[c][r];
    }
}

// ---------------- NT GEMM: C[m][n] = sum_k A[m][k]*B[n][k] ----------------
// m97 structure: 128x128 tile, 4 waves (2x2 of 64x64), BK=32,
// global_load_lds width-16 staging into linear LDS [128][32].
// MODE 0: bf16 out (QKV).  MODE 1: f32 out, *scale, causal.  MODE 2: f32 out,
// K truncated at m0+128.
template <int MODE>
__global__ __launch_bounds__(256) void gemm_nt(
    const short* __restrict__ A0, int lda, size_t sAz,
    const short* __restrict__ B0, int ldb, size_t sBz,
    void* __restrict__ C0, int ldc, size_t sCzBytes,
    int Ktotal, float scale) {

    const int m0 = blockIdx.y * 128;
    const int n0 = blockIdx.x * 128;
    if (MODE == 1 && n0 > m0 + 127) return;  // fully above diagonal

    const short* Ab = A0 + (size_t)blockIdx.z * sAz;
    const short* Bb = B0 + (size_t)blockIdx.z * sBz;
    char* Cb = (char*)C0 + (size_t)blockIdx.z * sCzBytes;

    const int tid = threadIdx.x;
    const int lane = tid & 63;
    const int wid = tid >> 6;
    const int wm = wid >> 1, wn = wid & 1;  // 2x2 waves, each 64x64

    // linear layout, NO padding (global_load_lds writes base + lane*16)
    __shared__ __align__(16) short As[128 * 32];
    __shared__ __align__(16) short Bs[128 * 32];

    f32x4 acc[4][4] = {};

    const int Kend = (MODE == 2) ? (m0 + 128 < Ktotal ? m0 + 128 : Ktotal) : Ktotal;
    const int r = lane & 15;
    const int kk = (lane >> 4) * 8;

    // staging geometry: idx = tid + i*256; row = idx>>2 (4 thr x 16B per 64B
    // row), kc = (idx&3)*8. LDS dest = idx*8 shorts = wave-uniform + lane*16B.
    const int srow = tid >> 2;
    const int scol = (tid & 3) * 8;

    const short* Agp = Ab + (size_t)(m0 + srow) * lda + scol;
    const short* Bgp = Bb + (size_t)(n0 + srow) * ldb + scol;
    const size_t a64 = (size_t)64 * lda;
    const size_t b64 = (size_t)64 * ldb;

    for (int k0 = 0; k0 < Kend; k0 += 32) {
        __syncthreads();
        GLOAD_LDS16(Agp + k0,       As + tid * 8);
        GLOAD_LDS16(Agp + k0 + a64, As + 2048 + tid * 8);
        GLOAD_LDS16(Bgp + k0,       Bs + tid * 8);
        GLOAD_LDS16(Bgp + k0 + b64, Bs + 2048 + tid * 8);
        __syncthreads();  // compiler drains vmcnt(0) before s_barrier

        bf16x8 a[4], b[4];
#pragma unroll
        for (int mi = 0; mi < 4; ++mi)
            a[mi] = *(bf16x8*)&As[(wm * 64 + mi * 16 + r) * 32 + kk];
#pragma unroll
        for (int ni = 0; ni < 4; ++ni)
            b[ni] = *(bf16x8*)&Bs[(wn * 64 + ni * 16 + r) * 32 + kk];
#pragma unroll
        for (int mi = 0; mi < 4; ++mi)
#pragma unroll
            for (int ni = 0; ni < 4; ++ni)
                acc[mi][ni] = __builtin_amdgcn_mfma_f32_16x16x32_bf16(
                    a[mi], b[ni], acc[mi][ni], 0, 0, 0);
    }

    // epilogue: C/D layout col=lane&15, row=(lane>>4)*4+reg
    const int r4 = (lane >> 4) * 4;
    const int c = lane & 15;
#pragma unroll
    for (int mi = 0; mi < 4; ++mi) {
#pragma unroll
        for (int ni = 0; ni < 4; ++ni) {
            int col = n0 + wn * 64 + ni * 16 + c;
#pragma unroll
            for (int i = 0; i < 4; ++i) {
                int rr = m0 + wm * 64 + mi * 16 + r4 + i;
                float v = acc[mi][ni][i];
                if (MODE == 0) {
                    ((short*)Cb)[(size_t)rr * ldc + col] = f2bf(v);
                } else if (MODE == 1) {
                    if (col <= rr)
                        ((float*)Cb)[(size_t)rr * ldc + col] = v * scale;
                } else {
                    ((float*)Cb)[(size_t)rr * ldc + col] = v;
                }
            }
        }
    }
}

// ---------------- causal row softmax, f32 scores -> bf16 attn in-place ------
__global__ __launch_bounds__(256) void softmax_causal(float* __restrict__ scores) {
    int row = blockIdx.x;            // 0..8191
    int b = row >> 11, i = row & 2047;
    float* srow = scores + ((size_t)b * 2048 + i) * 2048;
    short* arow = (short*)srow;      // bf16 written over the same row
    __shared__ float sv[2048];
    __shared__ float red[8];
    int t = threadIdx.x;
    int L = i + 1;

    float mx = -1e30f;
    for (int j = t; j < L; j += 256) {
        float v = srow[j];
        sv[j] = v;
        mx = fmaxf(mx, v);
    }
#pragma unroll
    for (int o = 32; o > 0; o >>= 1) mx = fmaxf(mx, __shfl_down(mx, o));
    if ((t & 63) == 0) red[t >> 6] = mx;
    __syncthreads();
    mx = fmaxf(fmaxf(red[0], red[1]), fmaxf(red[2], red[3]));

    float sum = 0.f;
    for (int j = t; j < L; j += 256) {
        float e = __expf(sv[j] - mx);
        sv[j] = e;
        sum += e;
    }
#pragma unroll
    for (int o = 32; o > 0; o >>= 1) sum += __shfl_down(sum, o);
    if ((t & 63) == 0) red[4 + (t >> 6)] = sum;
    __syncthreads();
    sum = red[4] + red[5] + red[6] + red[7];
    float rinv = 1.0f / sum;

    int Lpad = (i | 127) + 1;  // zero-fill up to the 128-block edge for PV
    for (int j = t; j < Lpad; j += 256) {
        float p = (j < L) ? sv[j] * rinv : 0.0f;
        arow[j] = f2bf(p);
    }
}

extern "C" void kernel_launch(void* const* d_in, const int* in_sizes, int n_in,
                              void* d_out, int out_size, void* d_ws, size_t ws_size,
                              hipStream_t stream) {
    const float* x  = (const float*)d_in[0];
    const float* wq = (const float*)d_in[1];
    const float* wk = (const float*)d_in[2];
    const float* wv = (const float*)d_in[3];
    float* out = (float*)d_out;

    // workspace layout (shorts)
    short* ws16 = (short*)d_ws;
    short* xb = ws16;                    //  8,388,608 shorts (16.78 MB)
    short* wt = xb + 8388608;            //  3,145,728
    short* qb = wt + 3145728;            //  8,388,608
    short* kb = qb + 8388608;            //  8,388,608
    short* vb = kb + 8388608;            //  8,388,608
    float* scores = (float*)(vb + 8388608);  // 4*2048*2048 f32 (67.1 MB)
    short* vt = xb;                      // reuse xb after QKV GEMM

    convx<<<8192, 256, 0, stream>>>(x, xb, 2097152);
    wtrans<<<dim3(16, 16, 3), 256, 0, stream>>>(wq, wk, wv, wt);
    // QKV: [8192,1024] = xb @ wt^T ; z selects weight & output
    gemm_nt<0><<<dim3(8, 64, 3), 256, 0, stream>>>(
        xb, 1024, (size_t)0,
        wt, 1024, (size_t)1048576,
        qb, 1024, (size_t)16777216,
        1024, 1.0f);
    vtrans<<<dim3(32, 16, 4), 256, 0, stream>>>(vb, vt);
    // scores = (q @ k^T) / 32, causal
    gemm_nt<1><<<dim3(16, 16, 4), 256, 0, stream>>>(
        qb, 1024, (size_t)2097152,
        kb, 1024, (size_t)2097152,
        scores, 2048, (size_t)16777216,
        1024, 0.03125f);
    softmax_causal<<<8192, 256, 0, stream>>>(scores);
    // out = attn @ vt^T, K truncated at diagonal; attn lda=4096 (in-place rows)
    gemm_nt<2><<<dim3(8, 16, 4), 256, 0, stream>>>(
        (const short*)scores, 4096, (size_t)8388608,
        vt, 2048, (size_t)2097152,
        out, 1024, (size_t)8388608,
        2048, 1.0f);
}

// Round 3
// 215.408 us; speedup vs baseline: 1.1542x; 1.0850x over previous
//
#include <hip/hip_runtime.h>
#include <hip/hip_bf16.h>

// B=4, S=2048, D=1024. x:[4,2048,1024] f32; wq/wk/wv:[1024,1024] f32.
// out:[4,2048,1024] f32.
//
// Pipeline (bf16 MFMA, fp32 accum):
//   1. convx:  x f32 -> xb bf16                        [8192,1024]
//   2. wtrans: wq/wk/wv f32 -> wt bf16 TRANSPOSED      [3][1024(n)][1024(k)]
//   3. gemm256<0>: qb,kb = xb @ wt[0:2]^T (N=2048 fused), bf16 out
//   4. gemm256<3>: vt = wt[2] @ xb^T  -> [4][1024(d)][2048(s)] bf16 (V^T direct)
//   5. gemm256<1>: scores = (qb @ kb^T)/32, causal block-skip, f32 out
//   6. softmax: causal row softmax, bf16 attn in-place, zero-pad to 256-edge
//   7. gemm256<2>: out = attn @ vt^T (Kend = m0+256), f32 out
//
// R3: 256x256 tile, BK=64, 8 waves (2Mx4N, wave tile 128x64), 128 KiB LDS
// double-buffer, global_load_lds width-16 staging one K-tile ahead,
// counted s_waitcnt vmcnt(8) + raw s_barrier (loads in flight across
// barrier — the T3/T4 lever), XOR LDS swizzle slot^=(row&7) (T2, applied
// both-sides: pre-swizzled global source + swizzled ds_read), setprio (T5).

typedef __attribute__((ext_vector_type(8))) short bf16x8;
typedef __attribute__((ext_vector_type(4))) float f32x4;

#define GLOAD_LDS16(g, l)                                                     \
    __builtin_amdgcn_global_load_lds(                                         \
        (const __attribute__((address_space(1))) void*)(g),                   \
        (__attribute__((address_space(3))) void*)(l), 16, 0, 0)

__device__ __forceinline__ short f2bf(float f) {
    union { float f; unsigned u; } v; v.f = f;
    unsigned r = v.u + 0x7FFFu + ((v.u >> 16) & 1u);
    return (short)(r >> 16);
}

// ---------------- convert x to bf16 ----------------
__global__ __launch_bounds__(256) void convx(const float* __restrict__ x,
                                             short* __restrict__ xb, int n4) {
    int i = blockIdx.x * 256 + threadIdx.x;
    if (i < n4) {
        float4 v = ((const float4*)x)[i];
        short4 o;
        o.x = f2bf(v.x); o.y = f2bf(v.y); o.z = f2bf(v.z); o.w = f2bf(v.w);
        ((short4*)xb)[i] = o;
    }
}

// ---------------- weights: f32 [k][n] -> bf16 [n][k] ----------------
__global__ __launch_bounds__(256) void wtrans(const float* __restrict__ wq,
                                              const float* __restrict__ wk,
                                              const float* __restrict__ wv,
                                              short* __restrict__ wt) {
    int w = blockIdx.z;
    const float* W = (w == 0) ? wq : (w == 1) ? wk : wv;
    short* O = wt + (size_t)w * 1048576;
    int n0 = blockIdx.x * 64, k0 = blockIdx.y * 64;
    __shared__ float tile[64][65];
    int t = threadIdx.x;
#pragma unroll
    for (int i = 0; i < 16; ++i) {
        int idx = t + i * 256;
        int r = idx >> 6, c = idx & 63;
        tile[r][c] = W[(size_t)(k0 + r) * 1024 + n0 + c];
    }
    __syncthreads();
#pragma unroll
    for (int i = 0; i < 16; ++i) {
        int idx = t + i * 256;
        int r = idx >> 6, c = idx & 63;
        O[(size_t)(n0 + r) * 1024 + k0 + c] = f2bf(tile[c][r]);
    }
}

// ---------------- 256x256 NT GEMM, pipelined ----------------
// C[m][n] = sum_k A[m][k] * B[n][k]
// MODE 0: QK-proj  (A=xb, B=wt[q,k]; bf16 out split qb/kb at col 1024)
// MODE 3: V^T-proj (A=wt[v], B=xb; bf16 out [4][1024][2048], col=b*2048+s)
// MODE 1: scores   (f32 out *scale, causal: skip n0>m0+255, pred col<=row)
// MODE 2: PV       (A=attn bf16 lda=4096, B=vt; f32 out; Kend=m0+256)
template <int MODE>
__global__ __launch_bounds__(512, 2) void gemm256(
    const short* __restrict__ A0, int lda, long long sA,
    const short* __restrict__ B0, int ldb, long long sB,
    void* __restrict__ C0, float scale) {

    const int m0 = blockIdx.y * 256;
    const int n0 = blockIdx.x * 256;
    if (MODE == 1 && n0 > m0 + 255) return;  // fully above diagonal
    const int z = blockIdx.z;
    const short* Ab = A0 + (size_t)z * sA;
    const short* Bb = B0 + (size_t)z * sB;

    const int tid = threadIdx.x;
    const int lane = tid & 63;
    const int wid = tid >> 6;
    const int wm = wid >> 2, wn = wid & 3;  // 2x4 waves, wave tile 128x64

    // [2 bufs][256 rows][64 cols] bf16 each => 2*32 KiB per matrix, 128 KiB
    __shared__ __align__(16) short As[2][16384];
    __shared__ __align__(16) short Bs[2][16384];

    f32x4 acc[8][4] = {};

    const int Kend = (MODE == 2) ? (m0 + 256) : 1024;
    const int nt = Kend >> 6;  // >= 4 always

    // ---- staging geometry: 8 threads/row, 16 B each, 4 issues per matrix.
    // Physical LDS slot (tid&7) holds logical slot (tid&7)^(row&7) so that
    // reads at phys = logical^(row&7) are conflict-free (2-way max).
    const int srow = tid >> 3;                       // 0..63
    const int sslotL = (tid & 7) ^ (srow & 7);       // row&7 == srow&7 (+64k rows)
    const short* Agp = Ab + (size_t)(m0 + srow) * lda + sslotL * 8;
    const short* Bgp = Bb + (size_t)(n0 + srow) * ldb + sslotL * 8;

#define STAGE(kt, bf)                                                         \
    do {                                                                      \
        const int _k0 = (kt) << 6;                                            \
        _Pragma("unroll") for (int i = 0; i < 4; ++i)                         \
            GLOAD_LDS16(Agp + _k0 + (size_t)(i * 64) * lda,                   \
                        &As[bf][i * 4096 + tid * 8]);                         \
        _Pragma("unroll") for (int i = 0; i < 4; ++i)                         \
            GLOAD_LDS16(Bgp + _k0 + (size_t)(i * 64) * ldb,                   \
                        &Bs[bf][i * 4096 + tid * 8]);                         \
    } while (0)

    const int r = lane & 15;
    const int g = lane >> 4;  // 16B-slot group 0..3

#define COMPUTE(bf)                                                           \
    do {                                                                      \
        _Pragma("unroll") for (int kk = 0; kk < 2; ++kk) {                    \
            bf16x8 a[8], b[4];                                                \
            _Pragma("unroll") for (int mi = 0; mi < 8; ++mi) {                \
                int row = wm * 128 + mi * 16 + r;                             \
                int sp = (kk * 4 + g) ^ (row & 7);                            \
                a[mi] = *(const bf16x8*)&As[bf][row * 64 + sp * 8];           \
            }                                                                 \
            _Pragma("unroll") for (int ni = 0; ni < 4; ++ni) {                \
                int row = wn * 64 + ni * 16 + r;                              \
                int sp = (kk * 4 + g) ^ (row & 7);                            \
                b[ni] = *(const bf16x8*)&Bs[bf][row * 64 + sp * 8];           \
            }                                                                 \
            __builtin_amdgcn_s_setprio(1);                                    \
            _Pragma("unroll") for (int mi = 0; mi < 8; ++mi)                  \
                _Pragma("unroll") for (int ni = 0; ni < 4; ++ni)              \
                    acc[mi][ni] = __builtin_amdgcn_mfma_f32_16x16x32_bf16(    \
                        a[mi], b[ni], acc[mi][ni], 0, 0, 0);                  \
            __builtin_amdgcn_s_setprio(0);                                    \
        }                                                                     \
    } while (0)

    // ---- pipelined K-loop: compute tile t from buf (t&1) while tile t+1's
    // 8 loads fly into buf ((t+1)&1). vmcnt(8) == "tile t landed, t+1 in
    // flight" — loads cross the barrier, never drained to 0 mid-loop.
    STAGE(0, 0);
    int buf = 0;
    for (int t = 0; t < nt - 1; ++t) {
        STAGE(t + 1, buf ^ 1);
        asm volatile("s_waitcnt vmcnt(8)" ::: "memory");
        __builtin_amdgcn_s_barrier();
        asm volatile("" ::: "memory");
        COMPUTE(buf);
        asm volatile("" ::: "memory");
        __builtin_amdgcn_s_barrier();  // all waves done reading buf before
                                       // next iteration's STAGE overwrites it
        buf ^= 1;
    }
    asm volatile("s_waitcnt vmcnt(0)" ::: "memory");
    __builtin_amdgcn_s_barrier();
    asm volatile("" ::: "memory");
    COMPUTE(buf);

    // ---- epilogue: C/D layout col=lane&15, row=(lane>>4)*4+reg
    const int r4 = (lane >> 4) * 4;
#pragma unroll
    for (int mi = 0; mi < 8; ++mi) {
#pragma unroll
        for (int ni = 0; ni < 4; ++ni) {
            int col = n0 + wn * 64 + ni * 16 + r;
#pragma unroll
            for (int i = 0; i < 4; ++i) {
                int rr = m0 + wm * 128 + mi * 16 + r4 + i;
                float v = acc[mi][ni][i];
                if (MODE == 0) {
                    // qb at 0, kb at +8388608 (adjacent buffers)
                    ((short*)C0)[(size_t)(col >> 10) * 8388608 +
                                 (size_t)rr * 1024 + (col & 1023)] = f2bf(v);
                } else if (MODE == 3) {
                    ((short*)C0)[(size_t)(col >> 11) * 2097152 +
                                 (size_t)rr * 2048 + (col & 2047)] = f2bf(v);
                } else if (MODE == 1) {
                    if (col <= rr)
                        ((float*)C0)[(size_t)z * 4194304 +
                                     (size_t)rr * 2048 + col] = v * scale;
                } else {
                    ((float*)C0)[(size_t)z * 2097152 +
                                 (size_t)rr * 1024 + col] = v;
                }
            }
        }
    }
#undef STAGE
#undef COMPUTE
}

// ---------------- causal row softmax, f32 scores -> bf16 attn in-place ------
__global__ __launch_bounds__(256) void softmax_causal(float* __restrict__ scores) {
    int row = blockIdx.x;            // 0..8191
    int b = row >> 11, i = row & 2047;
    float* srow = scores + ((size_t)b * 2048 + i) * 2048;
    short* arow = (short*)srow;      // bf16 written over the same row
    __shared__ float sv[2048];
    __shared__ float red[8];
    int t = threadIdx.x;
    int L = i + 1;

    float mx = -1e30f;
    for (int j = t; j < L; j += 256) {
        float v = srow[j];
        sv[j] = v;
        mx = fmaxf(mx, v);
    }
#pragma unroll
    for (int o = 32; o > 0; o >>= 1) mx = fmaxf(mx, __shfl_down(mx, o));
    if ((t & 63) == 0) red[t >> 6] = mx;
    __syncthreads();
    mx = fmaxf(fmaxf(red[0], red[1]), fmaxf(red[2], red[3]));

    float sum = 0.f;
    for (int j = t; j < L; j += 256) {
        float e = __expf(sv[j] - mx);
        sv[j] = e;
        sum += e;
    }
#pragma unroll
    for (int o = 32; o > 0; o >>= 1) sum += __shfl_down(sum, o);
    if ((t & 63) == 0) red[4 + (t >> 6)] = sum;
    __syncthreads();
    sum = red[4] + red[5] + red[6] + red[7];
    float rinv = 1.0f / sum;

    int Lpad = (i | 255) + 1;  // zero-fill to the 256-block edge for PV
    for (int j = t; j < Lpad; j += 256) {
        float p = (j < L) ? sv[j] * rinv : 0.0f;
        arow[j] = f2bf(p);
    }
}

extern "C" void kernel_launch(void* const* d_in, const int* in_sizes, int n_in,
                              void* d_out, int out_size, void* d_ws, size_t ws_size,
                              hipStream_t stream) {
    const float* x  = (const float*)d_in[0];
    const float* wq = (const float*)d_in[1];
    const float* wk = (const float*)d_in[2];
    const float* wv = (const float*)d_in[3];
    float* out = (float*)d_out;

    // workspace layout (shorts)
    short* ws16 = (short*)d_ws;
    short* xb = ws16;                    //  8,388,608 shorts
    short* wt = xb + 8388608;            //  3,145,728  [3][1024][1024]
    short* qb = wt + 3145728;            //  8,388,608  (kb must follow qb!)
    short* kb = qb + 8388608;            //  8,388,608
    short* vt = kb + 8388608;            //  8,388,608  [4][1024][2048]
    float* scores = (float*)(vt + 8388608);  // 4*2048*2048 f32

    convx<<<8192, 256, 0, stream>>>(x, xb, 2097152);
    wtrans<<<dim3(16, 16, 3), 256, 0, stream>>>(wq, wk, wv, wt);
    // Q,K fused: [8192 x 2048] = xb @ [wq^T;wk^T]^T
    gemm256<0><<<dim3(8, 32, 1), 512, 0, stream>>>(
        xb, 1024, 0LL, wt, 1024, 0LL, qb, 1.0f);
    // V^T: [1024 x 8192] = wt[v] @ xb^T
    gemm256<3><<<dim3(32, 4, 1), 512, 0, stream>>>(
        wt + 2097152, 1024, 0LL, xb, 1024, 0LL, vt, 1.0f);
    // scores = (q @ k^T)/32, causal
    gemm256<1><<<dim3(8, 8, 4), 512, 0, stream>>>(
        qb, 1024, 2097152LL, kb, 1024, 2097152LL, scores, 0.03125f);
    softmax_causal<<<8192, 256, 0, stream>>>(scores);
    // out = attn @ vt^T, Kend = m0+256
    gemm256<2><<<dim3(4, 8, 4), 512, 0, stream>>>(
        (const short*)scores, 4096, 8388608LL, vt, 2048, 2097152LL, out, 1.0f);
}

// Round 4
// 206.181 us; speedup vs baseline: 1.2059x; 1.0448x over previous
//
#include <hip/hip_runtime.h>
#include <hip/hip_bf16.h>

// B=4, S=2048, D=1024. x:[4,2048,1024] f32; wq/wk/wv:[1024,1024] f32.
// out:[4,2048,1024] f32.
//
// Pipeline (bf16 MFMA, fp32 accum):
//   1. convx:  x f32 -> xb bf16                        [8192,1024]
//   2. wtrans: wq/wk/wv f32 -> wt bf16 TRANSPOSED      [3][1024(n)][1024(k)]
//   3. gemm256<0>: qb,kb = xb @ wt[0:2]^T (N=2048 fused), bf16 out
//   4. gemm256<3>: vt = wt[2] @ xb^T  -> [4][1024(d)][2048(s)] bf16
//   5. gemm256<1>: scores = (qb @ kb^T)/32, causal block-skip, f32 out
//   6. softmax: causal row softmax, bf16 attn in-place, zero-pad to 256-edge
//   7. gemm256<2>: out = attn @ vt^T (Kend = m0+256), f32 out
//
// R4: true 8-phase schedule (m201 template). Per K-tile, 4 phases:
//   {ds_read 4-8 x b128 ; stage 1 half-tile of tile t+1 (2 gload_lds) ;
//    barrier ; lgkmcnt(0)+sched_barrier(0) ; setprio(1) ; 16 MFMA ;
//    setprio(0) ; barrier}
// Counted vmcnt(2) once per tile at phase 0 (after issuing next tile's
// first half-tile): in-order vmcnt => all of tile t's 8 loads landed,
// 2 loads stay in flight across the barrier. vmcnt(0) only in the peeled
// final tile. T2 XOR swizzle both-sides (R3 measured 0 conflicts), T5
// setprio (enabled by the phase split).

typedef __attribute__((ext_vector_type(8))) short bf16x8;
typedef __attribute__((ext_vector_type(4))) float f32x4;

#define GLOAD_LDS16(g, l)                                                     \
    __builtin_amdgcn_global_load_lds(                                         \
        (const __attribute__((address_space(1))) void*)(g),                   \
        (__attribute__((address_space(3))) void*)(l), 16, 0, 0)

__device__ __forceinline__ short f2bf(float f) {
    union { float f; unsigned u; } v; v.f = f;
    unsigned r = v.u + 0x7FFFu + ((v.u >> 16) & 1u);
    return (short)(r >> 16);
}

// ---------------- convert x to bf16 ----------------
__global__ __launch_bounds__(256) void convx(const float* __restrict__ x,
                                             short* __restrict__ xb, int n4) {
    int i = blockIdx.x * 256 + threadIdx.x;
    if (i < n4) {
        float4 v = ((const float4*)x)[i];
        short4 o;
        o.x = f2bf(v.x); o.y = f2bf(v.y); o.z = f2bf(v.z); o.w = f2bf(v.w);
        ((short4*)xb)[i] = o;
    }
}

// ---------------- weights: f32 [k][n] -> bf16 [n][k] ----------------
__global__ __launch_bounds__(256) void wtrans(const float* __restrict__ wq,
                                              const float* __restrict__ wk,
                                              const float* __restrict__ wv,
                                              short* __restrict__ wt) {
    int w = blockIdx.z;
    const float* W = (w == 0) ? wq : (w == 1) ? wk : wv;
    short* O = wt + (size_t)w * 1048576;
    int n0 = blockIdx.x * 64, k0 = blockIdx.y * 64;
    __shared__ float tile[64][65];
    int t = threadIdx.x;
#pragma unroll
    for (int i = 0; i < 16; ++i) {
        int idx = t + i * 256;
        int r = idx >> 6, c = idx & 63;
        tile[r][c] = W[(size_t)(k0 + r) * 1024 + n0 + c];
    }
    __syncthreads();
#pragma unroll
    for (int i = 0; i < 16; ++i) {
        int idx = t + i * 256;
        int r = idx >> 6, c = idx & 63;
        O[(size_t)(n0 + r) * 1024 + k0 + c] = f2bf(tile[c][r]);
    }
}

// ---------------- 256x256 NT GEMM, 8-phase pipelined ----------------
// C[m][n] = sum_k A[m][k] * B[n][k]
// MODE 0: QK-proj  (bf16 out split qb/kb at col 1024)
// MODE 3: V^T-proj (bf16 out [4][1024][2048], col=b*2048+s)
// MODE 1: scores   (f32 out *scale, causal)
// MODE 2: PV       (A=attn bf16 lda=4096; f32 out; Kend=m0+256)
template <int MODE>
__global__ __launch_bounds__(512, 2) void gemm256(
    const short* __restrict__ A0, int lda, long long sA,
    const short* __restrict__ B0, int ldb, long long sB,
    void* __restrict__ C0, float scale) {

    const int m0 = blockIdx.y * 256;
    const int n0 = blockIdx.x * 256;
    if (MODE == 1 && n0 > m0 + 255) return;  // fully above diagonal
    const int z = blockIdx.z;
    const short* Ab = A0 + (size_t)z * sA;
    const short* Bb = B0 + (size_t)z * sB;

    const int tid = threadIdx.x;
    const int lane = tid & 63;
    const int wid = tid >> 6;
    const int wm = wid >> 2, wn = wid & 3;  // 2x4 waves, wave tile 128x64

    // [buf][half][128 rows x 64 cols] bf16; total 128 KiB.
    // Wave wm reads only A-half wm; wave wn reads only B-half wn>>1.
    __shared__ __align__(16) short As[2][2][8192];
    __shared__ __align__(16) short Bs[2][2][8192];

    f32x4 acc[8][4] = {};

    const int Kend = (MODE == 2) ? (m0 + 256) : 1024;
    const int nt = Kend >> 6;  // >= 4 always

    // staging: 8 thr/row x 16B. Physical slot (tid&7) of row r holds logical
    // slot (tid&7)^(r&7)  =>  global src pre-swizzled, LDS dest linear
    // (dest offset = tid*8 within the half). Reader XORs the same involution.
    const int srow = tid >> 3;                  // 0..63
    const int sl = (tid & 7) ^ (srow & 7);
    const short* Agp = Ab + (size_t)(m0 + srow) * lda + sl * 8;
    const short* Bgp = Bb + (size_t)(n0 + srow) * ldb + sl * 8;

// stage half h of the A/B tile for K-tile kt into buffer bf (2 gloads)
#define SA(kt, bf, h)                                                         \
    do {                                                                      \
        const int _k = (kt) << 6;                                             \
        GLOAD_LDS16(Agp + _k + (size_t)((h)*128 + 0) * lda,                   \
                    &As[bf][h][tid * 8]);                                     \
        GLOAD_LDS16(Agp + _k + (size_t)((h)*128 + 64) * lda,                  \
                    &As[bf][h][4096 + tid * 8]);                              \
    } while (0)
#define SB(kt, bf, h)                                                         \
    do {                                                                      \
        const int _k = (kt) << 6;                                             \
        GLOAD_LDS16(Bgp + _k + (size_t)((h)*128 + 0) * ldb,                   \
                    &Bs[bf][h][tid * 8]);                                     \
        GLOAD_LDS16(Bgp + _k + (size_t)((h)*128 + 64) * ldb,                  \
                    &Bs[bf][h][4096 + tid * 8]);                              \
    } while (0)

    const int r = lane & 15;
    const int g = lane >> 4;
    const int pxor = r & 7;

#define LDA4(dst, bf, mh, kk)                                                 \
    _Pragma("unroll") for (int q = 0; q < 4; ++q)                             \
        dst[q] = *(const bf16x8*)&As[bf][wm][((mh)*64 + q * 16 + r) * 64 +    \
                                             (((kk)*4 + g) ^ pxor) * 8];
#define LDB4(dst, bf, kk)                                                     \
    _Pragma("unroll") for (int q = 0; q < 4; ++q)                             \
        dst[q] = *(const bf16x8*)&Bs[bf][wn >> 1][((wn & 1) * 64 + q * 16 +   \
                                                   r) * 64 +                  \
                                                  (((kk)*4 + g) ^ pxor) * 8];
#define LGKM0()                                                               \
    asm volatile("s_waitcnt lgkmcnt(0)" ::: "memory");                        \
    __builtin_amdgcn_sched_barrier(0)
#define MF16(mh, ar, br)                                                      \
    do {                                                                      \
        __builtin_amdgcn_s_setprio(1);                                        \
        _Pragma("unroll") for (int q = 0; q < 4; ++q)                         \
            _Pragma("unroll") for (int ni = 0; ni < 4; ++ni)                  \
                acc[(mh)*4 + q][ni] = __builtin_amdgcn_mfma_f32_16x16x32_bf16(\
                    ar[q], br[ni], acc[(mh)*4 + q][ni], 0, 0, 0);             \
        __builtin_amdgcn_s_setprio(0);                                        \
    } while (0)

    // prologue: fully stage K-tile 0
    SA(0, 0, 0); SA(0, 0, 1); SB(0, 0, 0); SB(0, 0, 1);
    int buf = 0;
    for (int t = 0; t < nt - 1; ++t) {
        const int nb = buf ^ 1;
        bf16x8 a[4], b[4];
        // phase 0 (kk0, mh0): issue next tile's first half, then counted wait
        SA(t + 1, nb, 0);
        asm volatile("s_waitcnt vmcnt(2)" ::: "memory");  // tile t all landed
        __builtin_amdgcn_s_barrier();
        LDA4(a, buf, 0, 0); LDB4(b, buf, 0);
        LGKM0();
        MF16(0, a, b);
        __builtin_amdgcn_s_barrier();
        // phase 1 (kk0, mh1)
        LDA4(a, buf, 1, 0);
        SB(t + 1, nb, 0);
        __builtin_amdgcn_s_barrier();
        LGKM0();
        MF16(1, a, b);
        __builtin_amdgcn_s_barrier();
        // phase 2 (kk1, mh0)
        LDA4(a, buf, 0, 1); LDB4(b, buf, 1);
        SA(t + 1, nb, 1);
        __builtin_amdgcn_s_barrier();
        LGKM0();
        MF16(0, a, b);
        __builtin_amdgcn_s_barrier();
        // phase 3 (kk1, mh1)
        LDA4(a, buf, 1, 1);
        SB(t + 1, nb, 1);
        __builtin_amdgcn_s_barrier();
        LGKM0();
        MF16(1, a, b);
        __builtin_amdgcn_s_barrier();
        buf = nb;
    }
    // epilogue: last tile, no staging, drain
    {
        bf16x8 a[4], b[4];
        asm volatile("s_waitcnt vmcnt(0)" ::: "memory");
        __builtin_amdgcn_s_barrier();
        LDA4(a, buf, 0, 0); LDB4(b, buf, 0);
        LGKM0();
        MF16(0, a, b);
        LDA4(a, buf, 1, 0);
        LGKM0();
        MF16(1, a, b);
        LDA4(a, buf, 0, 1); LDB4(b, buf, 1);
        LGKM0();
        MF16(0, a, b);
        LDA4(a, buf, 1, 1);
        LGKM0();
        MF16(1, a, b);
    }

    // ---- C epilogue: C/D layout col=lane&15, row=(lane>>4)*4+reg
    const int r4 = (lane >> 4) * 4;
#pragma unroll
    for (int mi = 0; mi < 8; ++mi) {
#pragma unroll
        for (int ni = 0; ni < 4; ++ni) {
            int col = n0 + wn * 64 + ni * 16 + r;
#pragma unroll
            for (int i = 0; i < 4; ++i) {
                int rr = m0 + wm * 128 + mi * 16 + r4 + i;
                float v = acc[mi][ni][i];
                if (MODE == 0) {
                    ((short*)C0)[(size_t)(col >> 10) * 8388608 +
                                 (size_t)rr * 1024 + (col & 1023)] = f2bf(v);
                } else if (MODE == 3) {
                    ((short*)C0)[(size_t)(col >> 11) * 2097152 +
                                 (size_t)rr * 2048 + (col & 2047)] = f2bf(v);
                } else if (MODE == 1) {
                    if (col <= rr)
                        ((float*)C0)[(size_t)z * 4194304 +
                                     (size_t)rr * 2048 + col] = v * scale;
                } else {
                    ((float*)C0)[(size_t)z * 2097152 +
                                 (size_t)rr * 1024 + col] = v;
                }
            }
        }
    }
#undef SA
#undef SB
#undef LDA4
#undef LDB4
#undef LGKM0
#undef MF16
}

// ---------------- causal row softmax, f32 scores -> bf16 attn in-place ------
__global__ __launch_bounds__(256) void softmax_causal(float* __restrict__ scores) {
    int row = blockIdx.x;            // 0..8191
    int b = row >> 11, i = row & 2047;
    float* srow = scores + ((size_t)b * 2048 + i) * 2048;
    short* arow = (short*)srow;      // bf16 written over the same row
    __shared__ float sv[2048];
    __shared__ float red[8];
    int t = threadIdx.x;
    int L = i + 1;

    float mx = -1e30f;
    for (int j = t; j < L; j += 256) {
        float v = srow[j];
        sv[j] = v;
        mx = fmaxf(mx, v);
    }
#pragma unroll
    for (int o = 32; o > 0; o >>= 1) mx = fmaxf(mx, __shfl_down(mx, o));
    if ((t & 63) == 0) red[t >> 6] = mx;
    __syncthreads();
    mx = fmaxf(fmaxf(red[0], red[1]), fmaxf(red[2], red[3]));

    float sum = 0.f;
    for (int j = t; j < L; j += 256) {
        float e = __expf(sv[j] - mx);
        sv[j] = e;
        sum += e;
    }
#pragma unroll
    for (int o = 32; o > 0; o >>= 1) sum += __shfl_down(sum, o);
    if ((t & 63) == 0) red[4 + (t >> 6)] = sum;
    __syncthreads();
    sum = red[4] + red[5] + red[6] + red[7];
    float rinv = 1.0f / sum;

    int Lpad = (i | 255) + 1;  // zero-fill to the 256-block edge for PV
    for (int j = t; j < Lpad; j += 256) {
        float p = (j < L) ? sv[j] * rinv : 0.0f;
        arow[j] = f2bf(p);
    }
}

extern "C" void kernel_launch(void* const* d_in, const int* in_sizes, int n_in,
                              void* d_out, int out_size, void* d_ws, size_t ws_size,
                              hipStream_t stream) {
    const float* x  = (const float*)d_in[0];
    const float* wq = (const float*)d_in[1];
    const float* wk = (const float*)d_in[2];
    const float* wv = (const float*)d_in[3];
    float* out = (float*)d_out;

    // workspace layout (shorts)
    short* ws16 = (short*)d_ws;
    short* xb = ws16;                    //  8,388,608 shorts
    short* wt = xb + 8388608;            //  3,145,728  [3][1024][1024]
    short* qb = wt + 3145728;            //  8,388,608  (kb must follow qb!)
    short* kb = qb + 8388608;            //  8,388,608
    short* vt = kb + 8388608;            //  8,388,608  [4][1024][2048]
    float* scores = (float*)(vt + 8388608);  // 4*2048*2048 f32

    convx<<<8192, 256, 0, stream>>>(x, xb, 2097152);
    wtrans<<<dim3(16, 16, 3), 256, 0, stream>>>(wq, wk, wv, wt);
    // Q,K fused: [8192 x 2048] = xb @ [wq^T;wk^T]^T
    gemm256<0><<<dim3(8, 32, 1), 512, 0, stream>>>(
        xb, 1024, 0LL, wt, 1024, 0LL, qb, 1.0f);
    // V^T: [1024 x 8192] = wt[v] @ xb^T
    gemm256<3><<<dim3(32, 4, 1), 512, 0, stream>>>(
        wt + 2097152, 1024, 0LL, xb, 1024, 0LL, vt, 1.0f);
    // scores = (q @ k^T)/32, causal
    gemm256<1><<<dim3(8, 8, 4), 512, 0, stream>>>(
        qb, 1024, 2097152LL, kb, 1024, 2097152LL, scores, 0.03125f);
    softmax_causal<<<8192, 256, 0, stream>>>(scores);
    // out = attn @ vt^T, Kend = m0+256
    gemm256<2><<<dim3(4, 8, 4), 512, 0, stream>>>(
        (const short*)scores, 4096, 8388608LL, vt, 2048, 2097152LL, out, 1.0f);
}